// Round 1
// baseline (951.851 us; speedup 1.0000x reference)
//
#include <hip/hip_runtime.h>

#define BDIM 4096
#define DDIM 4096
#define HDIM 1024

// ---------------- k1: h = relu(x@W1 + b1); partial_logit[row][ntile] = sum_j relu(h)*W2[j]
// fp64 accumulation to track the float64 numpy reference.
// grid (HDIM/64, BDIM/64), block 256 (16x16 threads, 4x4 outputs each)
__global__ __launch_bounds__(256) void k1_gemm(const float* __restrict__ x,
                                               const float* __restrict__ W1,
                                               const float* __restrict__ b1,
                                               const float* __restrict__ W2,
                                               double* __restrict__ plogit)
{
    __shared__ double As[16][66];   // [kk][m], padded: 528B row stride (16B aligned, banks spread)
    __shared__ double Bs[16][66];   // [kk][n]
    __shared__ double Ps[64][16];   // per-row partial-logit reduce

    const int tid = threadIdx.x;
    const int tx = tid & 15, ty = tid >> 4;
    const int n0 = blockIdx.x * 64;
    const int m0 = blockIdx.y * 64;

    double acc[4][4] = {};

    for (int k0 = 0; k0 < DDIM; k0 += 16) {
        #pragma unroll
        for (int i = 0; i < 4; i++) {
            int idx = tid + i * 256;
            int m = idx >> 4, kk = idx & 15;
            As[kk][m] = (double)x[(size_t)(m0 + m) * DDIM + (k0 + kk)];
        }
        #pragma unroll
        for (int i = 0; i < 4; i++) {
            int idx = tid + i * 256;
            int kk = idx >> 6, n = idx & 63;
            Bs[kk][n] = (double)W1[(size_t)(k0 + kk) * HDIM + (n0 + n)];
        }
        __syncthreads();
        #pragma unroll
        for (int kk = 0; kk < 16; kk++) {
            double a[4], b[4];
            #pragma unroll
            for (int i = 0; i < 4; i++) a[i] = As[kk][ty * 4 + i];
            #pragma unroll
            for (int j = 0; j < 4; j++) b[j] = Bs[kk][tx * 4 + j];
            #pragma unroll
            for (int i = 0; i < 4; i++)
                #pragma unroll
                for (int j = 0; j < 4; j++)
                    acc[i][j] += a[i] * b[j];
        }
        __syncthreads();
    }

    // epilogue: relu(acc + b1) * W2, partial per row
    #pragma unroll
    for (int i = 0; i < 4; i++) {
        double p = 0.0;
        #pragma unroll
        for (int j = 0; j < 4; j++) {
            int n = n0 + tx * 4 + j;
            double h = acc[i][j] + (double)b1[n];
            if (h > 0.0) p += h * (double)W2[n];
        }
        Ps[ty * 4 + i][tx] = p;
    }
    __syncthreads();
    if (tid < 64) {
        double s = 0.0;
        #pragma unroll
        for (int t = 0; t < 16; t++) s += Ps[tid][t];
        plogit[(size_t)(m0 + tid) * 16 + blockIdx.x] = s;
    }
}

// ---------------- k2: per-row — logit -> sigmoid -> k -> radix-select threshold ->
// mask/sparse_x/sparsity/actual_sparsity, row l1 to ws. One block (256 thr) per row.
__global__ __launch_bounds__(256) void k2_row(const float* __restrict__ x,
                                              const double* __restrict__ plogit,
                                              const float* __restrict__ b2,
                                              float* __restrict__ out_sparse,
                                              float* __restrict__ out_mask,
                                              float* __restrict__ out_spars,
                                              float* __restrict__ out_actual,
                                              float* __restrict__ l1rows)
{
    __shared__ unsigned bits[4096];
    __shared__ unsigned hist[256];
    __shared__ unsigned wsum[4];
    __shared__ int cnt_w[4];
    __shared__ float l1_w[4];
    __shared__ int sel_s;
    __shared__ unsigned selexc_s;
    __shared__ int k_s;

    const int row = blockIdx.x;
    const int tid = threadIdx.x;
    const int lane = tid & 63, wid = tid >> 6;
    const float* xr = x + (size_t)row * 4096;

    // load row as raw bits (keep sign; abs = bits & 0x7fffffff)
    for (int i = tid; i < 1024; i += 256) {
        uint4 v = ((const uint4*)xr)[i];
        bits[i * 4 + 0] = v.x;
        bits[i * 4 + 1] = v.y;
        bits[i * 4 + 2] = v.z;
        bits[i * 4 + 3] = v.w;
    }

    if (tid == 0) {
        double lg = 0.0;
        for (int t = 0; t < 16; t++) lg += plogit[(size_t)row * 16 + t];
        lg += (double)b2[0];
        double s  = 1.0 / (1.0 + exp(-lg));
        double sp = 0.05 + 0.25 * s;
        double kf = rint(4096.0 * (1.0 - sp));   // round-half-even, matches jnp/np.round
        int k = (int)kf;
        if (k < 1) k = 1;
        if (k > 4096) k = 4096;
        k_s = k;
        out_spars[row] = (float)sp;
    }
    __syncthreads();

    // 4-pass MSD radix select: kth smallest abs bit-pattern
    int krem = k_s;
    unsigned prefix = 0;
    for (int pass = 0; pass < 4; pass++) {
        int shift = 24 - pass * 8;
        hist[tid] = 0;
        __syncthreads();
        for (int i = tid; i < 4096; i += 256) {
            unsigned a = bits[i] & 0x7fffffffu;
            bool ok = (pass == 0) || ((a >> (shift + 8)) == prefix);
            if (ok) atomicAdd(&hist[(a >> shift) & 255u], 1u);
        }
        __syncthreads();
        // inclusive scan of 256 bins (4 waves of 64)
        unsigned v = hist[tid];
        unsigned sc = v;
        #pragma unroll
        for (int o = 1; o < 64; o <<= 1) {
            unsigned n = __shfl_up(sc, o, 64);
            if (lane >= o) sc += n;
        }
        if (lane == 63) wsum[wid] = sc;
        __syncthreads();
        unsigned off = 0;
        for (int w = 0; w < wid; w++) off += wsum[w];
        sc += off;
        unsigned exc = sc - v;                    // exclusive prefix
        if ((int)sc >= krem && (int)exc < krem) { // unique winner (v>0 required)
            sel_s = tid;
            selexc_s = exc;
        }
        __syncthreads();
        prefix = (prefix << 8) | (unsigned)sel_s;
        krem -= (int)selexc_s;
        __syncthreads();
    }
    const unsigned thr = prefix;   // bit pattern of kth smallest |x|

    // write outputs; count & l1
    int cnt = 0;
    float l1 = 0.0f;
    float* os = out_sparse + (size_t)row * 4096;
    float* om = out_mask + (size_t)row * 4096;
    for (int i = tid; i < 1024; i += 256) {
        float4 sv, mv;
        #pragma unroll
        for (int j = 0; j < 4; j++) {
            unsigned b = bits[i * 4 + j];
            unsigned a = b & 0x7fffffffu;
            bool m = a > thr;                      // == strict float > for nonneg floats
            float xv = __uint_as_float(b);
            float fa = __uint_as_float(a);
            (&sv.x)[j] = m ? xv : 0.0f;
            (&mv.x)[j] = m ? 1.0f : 0.0f;
            if (m) { cnt++; l1 += fa; }
        }
        ((float4*)os)[i] = sv;
        ((float4*)om)[i] = mv;
    }
    #pragma unroll
    for (int o = 32; o > 0; o >>= 1) {
        cnt += __shfl_down(cnt, o, 64);
        l1  += __shfl_down(l1,  o, 64);
    }
    if (lane == 0) { cnt_w[wid] = cnt; l1_w[wid] = l1; }
    __syncthreads();
    if (tid == 0) {
        int c   = cnt_w[0] + cnt_w[1] + cnt_w[2] + cnt_w[3];
        float l = l1_w[0] + l1_w[1] + l1_w[2] + l1_w[3];
        out_actual[row] = (float)c / 4096.0f;
        l1rows[row] = l;
    }
}

// ---------------- k3: deterministic l1 mean
__global__ __launch_bounds__(256) void k3_l1(const float* __restrict__ l1rows,
                                             float* __restrict__ out_l1)
{
    __shared__ double sm[256];
    int tid = threadIdx.x;
    double s = 0.0;
    for (int i = tid; i < 4096; i += 256) s += (double)l1rows[i];
    sm[tid] = s;
    __syncthreads();
    for (int st = 128; st > 0; st >>= 1) {
        if (tid < st) sm[tid] += sm[tid + st];
        __syncthreads();
    }
    if (tid == 0) out_l1[0] = (float)(sm[0] / 4096.0);
}

extern "C" void kernel_launch(void* const* d_in, const int* in_sizes, int n_in,
                              void* d_out, int out_size, void* d_ws, size_t ws_size,
                              hipStream_t stream)
{
    const float* x  = (const float*)d_in[0];
    const float* W1 = (const float*)d_in[1];
    const float* b1 = (const float*)d_in[2];
    const float* W2 = (const float*)d_in[3];
    const float* b2 = (const float*)d_in[4];

    float* out        = (float*)d_out;
    float* out_sparse = out;                       // [4096,4096]
    float* out_mask   = out + 16777216;            // [4096,4096]
    float* out_spars  = out + 33554432;            // [4096,1]
    float* out_actual = out + 33558528;            // [4096]
    float* out_l1     = out + 33562624;            // [1]

    double* plogit = (double*)d_ws;                            // 4096*16 doubles = 512 KB
    float*  l1rows = (float*)((char*)d_ws + 4096 * 16 * 8);    // 4096 floats

    k1_gemm<<<dim3(HDIM / 64, BDIM / 64), 256, 0, stream>>>(x, W1, b1, W2, plogit);
    k2_row<<<BDIM, 256, 0, stream>>>(x, plogit, b2, out_sparse, out_mask,
                                     out_spars, out_actual, l1rows);
    k3_l1<<<1, 256, 0, stream>>>(l1rows, out_l1);
}

// Round 3
// 187.071 us; speedup vs baseline: 5.0882x; 5.0882x over previous
//
#include <hip/hip_runtime.h>

typedef __attribute__((ext_vector_type(8))) short short8;
typedef __attribute__((ext_vector_type(4))) float f32x4;

// ---- d_out scratch (float offsets), consumed by k1est before k2 overwrites:
//   xa  bf16[16777216] -> [0, 8388608) floats
//   waT bf16[ 4194304] -> [8388608, 10485760) floats   (W1^T, [1024][4096])
// ---- d_ws layout (bytes; round 1 proved ws_size >= 540KB, we use 320KB):
//   plogit f32[4096*16]  [0, 262144)
//   k_arr  int[4096]     [262144, 278528)
//   sp_arr f32[4096]     [278528, 294912)
//   l1rows f64[4096]     [294912, 327680)

__device__ __forceinline__ unsigned short bf16rn(float f) {
    unsigned u = __float_as_uint(f);
    return (unsigned short)((u + 0x7fffu + ((u >> 16) & 1u)) >> 16);
}

// ---------------- k0a: x (fp32) -> xa (bf16)
__global__ __launch_bounds__(256) void k0a_cvtx(const float* __restrict__ x,
                                                unsigned short* __restrict__ xa)
{
    int i = blockIdx.x * 256 + threadIdx.x;          // 16384 blocks, 4 floats/thread
    float4 v = ((const float4*)x)[i];
    ushort4 a;
    a.x = bf16rn(v.x); a.y = bf16rn(v.y); a.z = bf16rn(v.z); a.w = bf16rn(v.w);
    ((ushort4*)xa)[i] = a;
}

// ---------------- k0b: W1 [4096][1024] fp32 -> waT [1024][4096] bf16 (transpose)
__global__ __launch_bounds__(256) void k0b_cvtw(const float* __restrict__ W1,
                                                unsigned short* __restrict__ waT)
{
    __shared__ float ts[64][65];
    const int n0 = blockIdx.x * 64;   // H tile
    const int k0 = blockIdx.y * 64;   // D tile
    const int tid = threadIdx.x;
    #pragma unroll
    for (int it = 0; it < 16; it++) {
        int idx = tid + it * 256;
        int r = idx >> 6, c = idx & 63;
        ts[r][c] = W1[(size_t)(k0 + r) * 1024 + (n0 + c)];
    }
    __syncthreads();
    #pragma unroll
    for (int it = 0; it < 16; it++) {
        int idx = tid + it * 256;
        int n = idx >> 6, kk = idx & 63;
        waT[(size_t)(n0 + n) * 4096 + (k0 + kk)] = bf16rn(ts[kk][n]);
    }
}

// ---------------- k1est: bf16 MFMA partial logits
// tile M=128 x N=64, K-step 32; 4 waves; wave w owns rows [w*32, w*32+32)
__global__ __launch_bounds__(256) void k1est(const unsigned short* __restrict__ xa,
                                             const unsigned short* __restrict__ waT,
                                             const float* __restrict__ b1,
                                             const float* __restrict__ W2,
                                             float* __restrict__ plogit)
{
    __shared__ alignas(16) unsigned short Axa[4][128][8];
    __shared__ alignas(16) unsigned short Bwa[4][64][8];

    // 512 blocks = 32 m-tiles x 16 n-tiles; XCD-chunked swizzle (512 % 8 == 0)
    const int bid = blockIdx.x;
    const int wgid = (bid & 7) * 64 + (bid >> 3);
    const int bn = wgid & 15, bm = wgid >> 4;
    const int n0 = bn * 64, m0 = bm * 128;
    const int tid = threadIdx.x;
    const int l = tid & 63, w = tid >> 6;
    const int arow = l & 15, kg = l >> 4;

    f32x4 acc[2][4];
    #pragma unroll
    for (int i = 0; i < 2; i++)
        #pragma unroll
        for (int j = 0; j < 4; j++) acc[i][j] = (f32x4)0.0f;

    for (int k0 = 0; k0 < 4096; k0 += 32) {
        {   // W tile: 64 rows x 32 k, 256 x 16B
            int n = tid >> 2, g = tid & 3;
            *(uint4*)&Bwa[g][n][0] = *(const uint4*)(waT + (size_t)(n0 + n) * 4096 + k0 + g * 8);
        }
        #pragma unroll
        for (int it = 0; it < 2; it++) {   // x tile: 128 rows x 32 k
            int idx = tid + it * 256;
            int row = idx >> 2, g = idx & 3;
            *(uint4*)&Axa[g][row][0] = *(const uint4*)(xa + (size_t)(m0 + row) * 4096 + k0 + g * 8);
        }
        __syncthreads();

        short8 af[2], bf[4];
        #pragma unroll
        for (int mf = 0; mf < 2; mf++)
            af[mf] = *(const short8*)&Axa[kg][w * 32 + mf * 16 + arow][0];
        #pragma unroll
        for (int nf = 0; nf < 4; nf++)
            bf[nf] = *(const short8*)&Bwa[kg][nf * 16 + arow][0];
        #pragma unroll
        for (int mf = 0; mf < 2; mf++)
            #pragma unroll
            for (int nf = 0; nf < 4; nf++)
                acc[mf][nf] = __builtin_amdgcn_mfma_f32_16x16x32_bf16(af[mf], bf[nf], acc[mf][nf], 0, 0, 0);
        __syncthreads();
    }

    // epilogue: h = acc + b1, relu, dot W2 over this block's 64 cols
    // C/D layout (m89): col = lane&15 (= N idx), row = (lane>>4)*4 + i (= M idx)
    #pragma unroll
    for (int mf = 0; mf < 2; mf++) {
        #pragma unroll
        for (int i = 0; i < 4; i++) {
            float p = 0.0f;
            #pragma unroll
            for (int nf = 0; nf < 4; nf++) {
                int n = n0 + nf * 16 + arow;
                float h = acc[mf][nf][i] + b1[n];
                if (h > 0.0f) p += h * W2[n];
            }
            #pragma unroll
            for (int o = 1; o < 16; o <<= 1) p += __shfl_xor(p, o, 64);
            if (arow == 0)
                plogit[(size_t)(m0 + w * 32 + mf * 16 + kg * 4 + i) * 16 + bn] = p;
        }
    }
}

// ---------------- k1b: per-row logit -> sigmoid -> sparsity/k
__global__ __launch_bounds__(256) void k1b_k(const float* __restrict__ plogit,
                                             const float* __restrict__ b2,
                                             int* __restrict__ k_arr,
                                             float* __restrict__ sp_arr)
{
    int row = blockIdx.x * 256 + threadIdx.x;
    float lg = 0.0f;
    #pragma unroll
    for (int t = 0; t < 16; t++) lg += plogit[(size_t)row * 16 + t];
    double s  = 1.0 / (1.0 + exp(-(double)(lg + b2[0])));
    double sp = 0.05 + 0.25 * s;
    int k = (int)rint(4096.0 * (1.0 - sp));
    if (k < 1) k = 1;
    if (k > 4096) k = 4096;
    k_arr[row] = k;
    sp_arr[row] = (float)sp;
}

// ---------------- k2: per-row radix-select threshold + all big outputs
__global__ __launch_bounds__(256) void k2_row(const float* __restrict__ x,
                                              const int* __restrict__ k_arr,
                                              const float* __restrict__ sp_arr,
                                              float* __restrict__ out_sparse,
                                              float* __restrict__ out_mask,
                                              float* __restrict__ out_spars,
                                              float* __restrict__ out_actual,
                                              double* __restrict__ l1rows)
{
    __shared__ unsigned bits[4096];
    __shared__ unsigned hist[256];
    __shared__ unsigned wsum[4];
    __shared__ int cnt_w[4];
    __shared__ double l1_w[4];
    __shared__ int sel_s;
    __shared__ unsigned selexc_s;

    const int row = blockIdx.x;
    const int tid = threadIdx.x;
    const int lane = tid & 63, wid = tid >> 6;
    const float* xr = x + (size_t)row * 4096;

    for (int i = tid; i < 1024; i += 256) {
        uint4 v = ((const uint4*)xr)[i];
        bits[i * 4 + 0] = v.x;
        bits[i * 4 + 1] = v.y;
        bits[i * 4 + 2] = v.z;
        bits[i * 4 + 3] = v.w;
    }
    if (tid == 0) out_spars[row] = sp_arr[row];
    __syncthreads();

    int krem = k_arr[row];
    unsigned prefix = 0;
    for (int pass = 0; pass < 4; pass++) {
        int shift = 24 - pass * 8;
        hist[tid] = 0;
        __syncthreads();
        for (int i = tid; i < 4096; i += 256) {
            unsigned a = bits[i] & 0x7fffffffu;
            bool ok = (pass == 0) || ((a >> (shift + 8)) == prefix);
            if (ok) atomicAdd(&hist[(a >> shift) & 255u], 1u);
        }
        __syncthreads();
        unsigned v = hist[tid];
        unsigned sc = v;
        #pragma unroll
        for (int o = 1; o < 64; o <<= 1) {
            unsigned n = __shfl_up(sc, o, 64);
            if (lane >= o) sc += n;
        }
        if (lane == 63) wsum[wid] = sc;
        __syncthreads();
        unsigned off = 0;
        for (int ww = 0; ww < wid; ww++) off += wsum[ww];
        sc += off;
        unsigned exc = sc - v;
        if ((int)sc >= krem && (int)exc < krem) { sel_s = tid; selexc_s = exc; }
        __syncthreads();
        prefix = (prefix << 8) | (unsigned)sel_s;
        krem -= (int)selexc_s;
        __syncthreads();
    }
    const unsigned thr = prefix;   // bit pattern of kth smallest |x|

    int cnt = 0;
    double l1 = 0.0;
    float* os = out_sparse + (size_t)row * 4096;
    float* om = out_mask + (size_t)row * 4096;
    for (int i = tid; i < 1024; i += 256) {
        float4 sv, mv;
        #pragma unroll
        for (int j = 0; j < 4; j++) {
            unsigned b = bits[i * 4 + j];
            unsigned a = b & 0x7fffffffu;
            bool m = a > thr;                  // strict float > for nonneg floats
            (&sv.x)[j] = m ? __uint_as_float(b) : 0.0f;
            (&mv.x)[j] = m ? 1.0f : 0.0f;
            if (m) { cnt++; l1 += (double)__uint_as_float(a); }
        }
        ((float4*)os)[i] = sv;
        ((float4*)om)[i] = mv;
    }
    #pragma unroll
    for (int o = 32; o > 0; o >>= 1) {
        cnt += __shfl_down(cnt, o, 64);
        l1  += __shfl_down(l1,  o, 64);
    }
    if (lane == 0) { cnt_w[wid] = cnt; l1_w[wid] = l1; }
    __syncthreads();
    if (tid == 0) {
        int c    = cnt_w[0] + cnt_w[1] + cnt_w[2] + cnt_w[3];
        double l = l1_w[0] + l1_w[1] + l1_w[2] + l1_w[3];
        out_actual[row] = (float)c / 4096.0f;
        l1rows[row] = l;
    }
}

// ---------------- k3: deterministic l1 mean (f64)
__global__ __launch_bounds__(256) void k3_l1(const double* __restrict__ l1rows,
                                             float* __restrict__ out_l1)
{
    __shared__ double sm[256];
    int tid = threadIdx.x;
    double s = 0.0;
    for (int i = tid; i < 4096; i += 256) s += l1rows[i];
    sm[tid] = s;
    __syncthreads();
    for (int st = 128; st > 0; st >>= 1) {
        if (tid < st) sm[tid] += sm[tid + st];
        __syncthreads();
    }
    if (tid == 0) out_l1[0] = (float)(sm[0] / 4096.0);
}

extern "C" void kernel_launch(void* const* d_in, const int* in_sizes, int n_in,
                              void* d_out, int out_size, void* d_ws, size_t ws_size,
                              hipStream_t stream)
{
    const float* x  = (const float*)d_in[0];
    const float* W1 = (const float*)d_in[1];
    const float* b1 = (const float*)d_in[2];
    const float* W2 = (const float*)d_in[3];
    const float* b2 = (const float*)d_in[4];

    float* out        = (float*)d_out;
    float* out_sparse = out;                       // [4096,4096]
    float* out_mask   = out + 16777216;            // [4096,4096]
    float* out_spars  = out + 33554432;            // [4096,1]
    float* out_actual = out + 33558528;            // [4096]
    float* out_l1     = out + 33562624;            // [1]

    // big scratch inside d_out's sparse region (consumed by k1est before k2 writes)
    unsigned short* xa  = (unsigned short*)(out);             // 32MB
    unsigned short* waT = (unsigned short*)(out + 8388608);   // 8MB

    // small hot arrays in d_ws (NO aliasing with outputs -> no races)
    char* ws = (char*)d_ws;
    float*  plogit = (float*)(ws);             // 256KB
    int*    k_arr  = (int*)(ws + 262144);      // 16KB
    float*  sp_arr = (float*)(ws + 278528);    // 16KB
    double* l1rows = (double*)(ws + 294912);   // 32KB  (8B aligned)

    k0a_cvtx<<<16384, 256, 0, stream>>>(x, xa);
    k0b_cvtw<<<dim3(16, 64), 256, 0, stream>>>(W1, waT);
    k1est<<<512, 256, 0, stream>>>(xa, waT, b1, W2, plogit);
    k1b_k<<<16, 256, 0, stream>>>(plogit, b2, k_arr, sp_arr);
    k2_row<<<4096, 256, 0, stream>>>(x, k_arr, sp_arr, out_sparse, out_mask,
                                     out_spars, out_actual, l1rows);
    k3_l1<<<1, 256, 0, stream>>>(l1rows, out_l1);
}